// Round 1
// baseline (3022.919 us; speedup 1.0000x reference)
//
#include <hip/hip_runtime.h>

// Problem constants (from reference)
#define N_NODES 100000
#define E_EDGES 1600000
#define DIM     128

// Workspace layout (bytes):
//   agg   : N*128 f32  @ 0          (51,200,000)
//   cnt   : N     f32  @ 51,200,000 (   400,000)
//   h     : N*128 f32  @ 51,600,000 (51,200,000)
//   WcatT : 256*128 f32@102,800,000 (   131,072)
// total ~98.2 MiB
#define AGG_OFF 0
#define CNT_OFF 51200000
#define H_OFF   51600000
#define WT_OFF  102800000

// ---------------- Kernel 1: LayerNorm + ReLU (one wave per row) --------------
__global__ __launch_bounds__(256) void k_ln_relu(const float* __restrict__ x,
                                                 const float* __restrict__ lw,
                                                 const float* __restrict__ lb,
                                                 float* __restrict__ h) {
  int row  = blockIdx.x * 4 + (threadIdx.x >> 6);
  int lane = threadIdx.x & 63;
  const float2* x2 = (const float2*)(x + (size_t)row * DIM);
  float2 v = x2[lane];
  float s  = v.x + v.y;
  float sq = v.x * v.x + v.y * v.y;
  #pragma unroll
  for (int off = 32; off > 0; off >>= 1) {
    s  += __shfl_xor(s, off);
    sq += __shfl_xor(sq, off);
  }
  float mu  = s * (1.0f / 128.0f);
  float var = sq * (1.0f / 128.0f) - mu * mu;
  float rs  = rsqrtf(var + 1e-5f);
  float2 w = ((const float2*)lw)[lane];
  float2 b = ((const float2*)lb)[lane];
  float2 o;
  o.x = fmaxf((v.x - mu) * rs * w.x + b.x, 0.0f);
  o.y = fmaxf((v.y - mu) * rs * w.y + b.y, 0.0f);
  ((float2*)(h + (size_t)row * DIM))[lane] = o;
}

// ------------- Kernel 2: pack transposed concat weights WcatT[k][c] ----------
// k in [0,256): k<128 -> W_l[c][k], else W_r[c][k-128]
__global__ __launch_bounds__(256) void k_pack_w(const float* __restrict__ Wl,
                                                const float* __restrict__ Wr,
                                                float* __restrict__ wt) {
  int i = blockIdx.x * 256 + threadIdx.x;  // 0..32767
  int k = i >> 7;
  int c = i & 127;
  wt[i] = (k < 128) ? Wl[c * 128 + k] : Wr[c * 128 + (k - 128)];
}

// ---------------- Kernel 3: edge scatter (mean numerator + counts) -----------
// 32 threads per edge, each thread handles 4 consecutive floats (float4 read).
__global__ __launch_bounds__(256) void k_scatter(const int* __restrict__ ei,
                                                 const float* __restrict__ h,
                                                 float* __restrict__ agg,
                                                 float* __restrict__ cnt) {
  long long tid = (long long)blockIdx.x * 256 + threadIdx.x;
  int e = (int)(tid >> 5);
  int q = (int)(tid & 31);
  int src = ei[e];
  int dst = ei[E_EDGES + e];
  float4 v = ((const float4*)(h + (size_t)src * DIM))[q];
  float* a = agg + (size_t)dst * DIM + q * 4;
  atomicAdd(a + 0, v.x);
  atomicAdd(a + 1, v.y);
  atomicAdd(a + 2, v.z);
  atomicAdd(a + 3, v.w);
  if (q == 0) atomicAdd(cnt + dst, 1.0f);
}

// ---------------- Kernel 4: fused scale + single GEMM (K=256) ----------------
// out[n][c] = sum_k [agg[n]*inv | h[n]](k) * WcatT[k][c] + b_l[c]
// Tile: 32 rows x 128 cols per block; 256 threads; 4x4 register tile each.
#define TM    32
#define PITCH 260  // 256 + 4 pad: keeps float4 16B alignment, breaks bank stride
__global__ __launch_bounds__(256) void k_gemm(const float* __restrict__ agg,
                                              const float* __restrict__ cnt,
                                              const float* __restrict__ h,
                                              const float* __restrict__ wt,
                                              const float* __restrict__ bl,
                                              float* __restrict__ out) {
  __shared__ float A[TM * PITCH];
  __shared__ float sinv[TM];
  int tid   = threadIdx.x;
  int rbase = blockIdx.x * TM;

  if (tid < TM) {
    float c = cnt[rbase + tid];
    sinv[tid] = 1.0f / fmaxf(c, 1.0f);
  }
  __syncthreads();

  // Stage A tile: 32 rows x 256 k  (2048 float4, 8 per thread), scaling agg.
  #pragma unroll
  for (int i = 0; i < 8; ++i) {
    int f   = tid + i * 256;   // 0..2047
    int row = f >> 6;          // 0..31
    int q   = f & 63;          // float4 index within row (64 per row)
    float4 v;
    if (q < 32) {
      v = ((const float4*)(agg + (size_t)(rbase + row) * DIM))[q];
      float s = sinv[row];
      v.x *= s; v.y *= s; v.z *= s; v.w *= s;
    } else {
      v = ((const float4*)(h + (size_t)(rbase + row) * DIM))[q - 32];
    }
    *((float4*)&A[row * PITCH + q * 4]) = v;
  }
  __syncthreads();

  int tx = tid & 31;   // cols tx*4 .. tx*4+3
  int ty = tid >> 5;   // rows ty*4 .. ty*4+3
  float acc[4][4];
  #pragma unroll
  for (int i = 0; i < 4; ++i)
    #pragma unroll
    for (int j = 0; j < 4; ++j) acc[i][j] = 0.0f;

  const float* Abase = &A[(ty * 4) * PITCH];
  #pragma unroll 4
  for (int k = 0; k < 256; ++k) {
    float4 w = ((const float4*)(wt + k * DIM))[tx];  // coalesced, L1/L2-hot
    float a0 = Abase[0 * PITCH + k];
    float a1 = Abase[1 * PITCH + k];
    float a2 = Abase[2 * PITCH + k];
    float a3 = Abase[3 * PITCH + k];
    acc[0][0] += a0 * w.x; acc[0][1] += a0 * w.y; acc[0][2] += a0 * w.z; acc[0][3] += a0 * w.w;
    acc[1][0] += a1 * w.x; acc[1][1] += a1 * w.y; acc[1][2] += a1 * w.z; acc[1][3] += a1 * w.w;
    acc[2][0] += a2 * w.x; acc[2][1] += a2 * w.y; acc[2][2] += a2 * w.z; acc[2][3] += a2 * w.w;
    acc[3][0] += a3 * w.x; acc[3][1] += a3 * w.y; acc[3][2] += a3 * w.z; acc[3][3] += a3 * w.w;
  }

  float4 bias = ((const float4*)bl)[tx];
  #pragma unroll
  for (int i = 0; i < 4; ++i) {
    float4 o;
    o.x = acc[i][0] + bias.x;
    o.y = acc[i][1] + bias.y;
    o.z = acc[i][2] + bias.z;
    o.w = acc[i][3] + bias.w;
    ((float4*)(out + (size_t)(rbase + ty * 4 + i) * DIM))[tx] = o;
  }
}

extern "C" void kernel_launch(void* const* d_in, const int* in_sizes, int n_in,
                              void* d_out, int out_size, void* d_ws, size_t ws_size,
                              hipStream_t stream) {
  const float* x  = (const float*)d_in[0];
  const int*   ei = (const int*)d_in[1];   // [2, E] int32
  const float* lw = (const float*)d_in[2];
  const float* lb = (const float*)d_in[3];
  const float* Wl = (const float*)d_in[4];
  const float* bl = (const float*)d_in[5];
  const float* Wr = (const float*)d_in[6];
  float* out = (float*)d_out;

  char* ws = (char*)d_ws;
  float* agg = (float*)(ws + AGG_OFF);
  float* cnt = (float*)(ws + CNT_OFF);
  float* h   = (float*)(ws + H_OFF);
  float* wt  = (float*)(ws + WT_OFF);

  // Zero agg + cnt (contiguous) — ws is re-poisoned to 0xAA before every call.
  hipMemsetAsync(agg, 0, (size_t)CNT_OFF + (size_t)N_NODES * 4 - AGG_OFF, stream);

  k_ln_relu<<<N_NODES / 4, 256, 0, stream>>>(x, lw, lb, h);
  k_pack_w<<<(256 * 128) / 256, 256, 0, stream>>>(Wl, Wr, wt);
  k_scatter<<<(int)(((long long)E_EDGES * 32) / 256), 256, 0, stream>>>(ei, h, agg, cnt);
  k_gemm<<<N_NODES / TM, 256, 0, stream>>>(agg, cnt, h, wt, bl, out);
}

// Round 2
// 625.568 us; speedup vs baseline: 4.8323x; 4.8323x over previous
//
#include <hip/hip_runtime.h>

#define N_NODES 100000
#define E_EDGES 1600000
#define DIM     128

// Workspace layout (bytes), total ~56.2 MiB:
#define H_OFF    0            // N*128 f32 = 51,200,000
#define WT_OFF   51200000     // 256*128 f32 = 131,072
#define DEG_OFF  51331072     // N int = 400,000
#define OFFS_OFF 51731072     // (N+1) int = 400,004 (pad to 8)
#define CUR_OFF  52131080     // N int = 400,000
#define BSUM_OFF 52531080     // 98 int (pad 512)
#define SRC_OFF  52531592     // E int = 6,400,000  -> end 58,931,592

#define SCAN_BLOCKS 98        // 98 * 1024 = 100,352 >= N

// ---------------- LayerNorm + ReLU (one wave per row) ------------------------
__global__ __launch_bounds__(256) void k_ln_relu(const float* __restrict__ x,
                                                 const float* __restrict__ lw,
                                                 const float* __restrict__ lb,
                                                 float* __restrict__ h) {
  int row  = blockIdx.x * 4 + (threadIdx.x >> 6);
  int lane = threadIdx.x & 63;
  float2 v = ((const float2*)(x + (size_t)row * DIM))[lane];
  float s  = v.x + v.y;
  float sq = v.x * v.x + v.y * v.y;
  #pragma unroll
  for (int off = 32; off > 0; off >>= 1) {
    s  += __shfl_xor(s, off);
    sq += __shfl_xor(sq, off);
  }
  float mu  = s * (1.0f / 128.0f);
  float var = sq * (1.0f / 128.0f) - mu * mu;
  float rs  = rsqrtf(var + 1e-5f);
  float2 w = ((const float2*)lw)[lane];
  float2 b = ((const float2*)lb)[lane];
  float2 o;
  o.x = fmaxf((v.x - mu) * rs * w.x + b.x, 0.0f);
  o.y = fmaxf((v.y - mu) * rs * w.y + b.y, 0.0f);
  ((float2*)(h + (size_t)row * DIM))[lane] = o;
}

// ---------------- pack transposed concat weights WcatT[k][c] -----------------
__global__ __launch_bounds__(256) void k_pack_w(const float* __restrict__ Wl,
                                                const float* __restrict__ Wr,
                                                float* __restrict__ wt) {
  int i = blockIdx.x * 256 + threadIdx.x;  // 0..32767
  int k = i >> 7;
  int c = i & 127;
  wt[i] = (k < 128) ? Wl[c * 128 + k] : Wr[c * 128 + (k - 128)];
}

// ---------------- degree histogram (1 atomic per edge) -----------------------
__global__ __launch_bounds__(256) void k_count(const int* __restrict__ ei,
                                               int* __restrict__ deg) {
  int e = blockIdx.x * 256 + threadIdx.x;
  atomicAdd(&deg[ei[E_EDGES + e]], 1);
}

// ---------------- scan stage 1: per-block exclusive scan (1024 elems) --------
__global__ __launch_bounds__(256) void k_scan1(const int* __restrict__ deg,
                                               int* __restrict__ offs,
                                               int* __restrict__ bsum) {
  __shared__ int s[256];
  int t = threadIdx.x;
  int base = blockIdx.x * 1024 + t * 4;
  int a0 = (base + 0 < N_NODES) ? deg[base + 0] : 0;
  int a1 = (base + 1 < N_NODES) ? deg[base + 1] : 0;
  int a2 = (base + 2 < N_NODES) ? deg[base + 2] : 0;
  int a3 = (base + 3 < N_NODES) ? deg[base + 3] : 0;
  s[t] = a0 + a1 + a2 + a3;
  __syncthreads();
  #pragma unroll
  for (int off = 1; off < 256; off <<= 1) {
    int x = (t >= off) ? s[t - off] : 0;
    __syncthreads();
    s[t] += x;
    __syncthreads();
  }
  int excl = (t > 0) ? s[t - 1] : 0;
  if (t == 255) bsum[blockIdx.x] = s[255];
  if (base + 0 < N_NODES) offs[base + 0] = excl;
  if (base + 1 < N_NODES) offs[base + 1] = excl + a0;
  if (base + 2 < N_NODES) offs[base + 2] = excl + a0 + a1;
  if (base + 3 < N_NODES) offs[base + 3] = excl + a0 + a1 + a2;
}

// ---------------- scan stage 2: exclusive scan of 98 block sums --------------
__global__ __launch_bounds__(128) void k_scan2(int* __restrict__ bsum) {
  __shared__ int s[128];
  int t = threadIdx.x;
  int v = (t < SCAN_BLOCKS) ? bsum[t] : 0;
  s[t] = v;
  __syncthreads();
  #pragma unroll
  for (int off = 1; off < 128; off <<= 1) {
    int x = (t >= off) ? s[t - off] : 0;
    __syncthreads();
    s[t] += x;
    __syncthreads();
  }
  if (t < SCAN_BLOCKS) bsum[t] = (t > 0) ? s[t - 1] : 0;
}

// ---------------- scan stage 3: add block bases; init cursor -----------------
__global__ __launch_bounds__(256) void k_scan3(int* __restrict__ offs,
                                               const int* __restrict__ bsum,
                                               int* __restrict__ cur) {
  int i = blockIdx.x * 256 + threadIdx.x;
  if (i < N_NODES) {
    int v = offs[i] + bsum[i >> 10];
    offs[i] = v;
    cur[i] = v;
  }
  if (i == N_NODES) offs[N_NODES] = E_EDGES;
}

// ---------------- CSR fill: 1 atomic per edge --------------------------------
__global__ __launch_bounds__(256) void k_fill(const int* __restrict__ ei,
                                              int* __restrict__ cur,
                                              int* __restrict__ srcidx) {
  int e = blockIdx.x * 256 + threadIdx.x;
  int src = ei[e];
  int dst = ei[E_EDGES + e];
  int pos = atomicAdd(&cur[dst], 1);
  srcidx[pos] = src;
}

// ---------------- fused gather + mean + GEMM ---------------------------------
// Block: 32 rows. Phase 1: each wave gathers/means 8 rows into LDS A-tile
// (cols 0..127 = scaled neighbor mean, 128..255 = h row). Phase 2: 4x4
// register-tile GEMM vs WcatT, +bias, store.
#define TM    32
#define PITCH 260
__global__ __launch_bounds__(256) void k_gather_gemm(const float* __restrict__ h,
                                                     const float* __restrict__ wt,
                                                     const float* __restrict__ bl,
                                                     const int* __restrict__ offs,
                                                     const int* __restrict__ srcidx,
                                                     float* __restrict__ out) {
  __shared__ float A[TM * PITCH];
  int tid  = threadIdx.x;
  int wave = tid >> 6;
  int lane = tid & 63;
  int rbase = blockIdx.x * TM;

  // Phase 1: gather
  for (int r8 = 0; r8 < 8; ++r8) {
    int row = wave * 8 + r8;
    int n   = rbase + row;
    int beg = offs[n];
    int end = offs[n + 1];
    float accx = 0.0f, accy = 0.0f;
    for (int j0 = beg; j0 < end; j0 += 64) {
      int rem = end - j0;
      int idx = (lane < rem) ? srcidx[j0 + lane] : 0;
      int cnt = rem < 64 ? rem : 64;
      for (int k = 0; k < cnt; ++k) {
        int s = __shfl(idx, k);
        float2 v = ((const float2*)(h + (size_t)s * DIM))[lane];
        accx += v.x;
        accy += v.y;
      }
    }
    float inv = 1.0f / fmaxf((float)(end - beg), 1.0f);
    float2 hv = ((const float2*)(h + (size_t)n * DIM))[lane];
    *((float2*)&A[row * PITCH + lane * 2])       = make_float2(accx * inv, accy * inv);
    *((float2*)&A[row * PITCH + 128 + lane * 2]) = hv;
  }
  __syncthreads();

  // Phase 2: GEMM
  int tx = tid & 31;
  int ty = tid >> 5;
  float acc[4][4];
  #pragma unroll
  for (int i = 0; i < 4; ++i)
    #pragma unroll
    for (int j = 0; j < 4; ++j) acc[i][j] = 0.0f;

  const float* Abase = &A[(ty * 4) * PITCH];
  #pragma unroll 4
  for (int k = 0; k < 256; ++k) {
    float4 w = ((const float4*)(wt + k * DIM))[tx];
    float a0 = Abase[0 * PITCH + k];
    float a1 = Abase[1 * PITCH + k];
    float a2 = Abase[2 * PITCH + k];
    float a3 = Abase[3 * PITCH + k];
    acc[0][0] += a0 * w.x; acc[0][1] += a0 * w.y; acc[0][2] += a0 * w.z; acc[0][3] += a0 * w.w;
    acc[1][0] += a1 * w.x; acc[1][1] += a1 * w.y; acc[1][2] += a1 * w.z; acc[1][3] += a1 * w.w;
    acc[2][0] += a2 * w.x; acc[2][1] += a2 * w.y; acc[2][2] += a2 * w.z; acc[2][3] += a2 * w.w;
    acc[3][0] += a3 * w.x; acc[3][1] += a3 * w.y; acc[3][2] += a3 * w.z; acc[3][3] += a3 * w.w;
  }

  float4 bias = ((const float4*)bl)[tx];
  #pragma unroll
  for (int i = 0; i < 4; ++i) {
    float4 o;
    o.x = acc[i][0] + bias.x;
    o.y = acc[i][1] + bias.y;
    o.z = acc[i][2] + bias.z;
    o.w = acc[i][3] + bias.w;
    ((float4*)(out + (size_t)(rbase + ty * 4 + i) * DIM))[tx] = o;
  }
}

extern "C" void kernel_launch(void* const* d_in, const int* in_sizes, int n_in,
                              void* d_out, int out_size, void* d_ws, size_t ws_size,
                              hipStream_t stream) {
  const float* x  = (const float*)d_in[0];
  const int*   ei = (const int*)d_in[1];   // [2, E] int32
  const float* lw = (const float*)d_in[2];
  const float* lb = (const float*)d_in[3];
  const float* Wl = (const float*)d_in[4];
  const float* bl = (const float*)d_in[5];
  const float* Wr = (const float*)d_in[6];
  float* out = (float*)d_out;

  char* ws = (char*)d_ws;
  float* h      = (float*)(ws + H_OFF);
  float* wt     = (float*)(ws + WT_OFF);
  int*   deg    = (int*)(ws + DEG_OFF);
  int*   offs   = (int*)(ws + OFFS_OFF);
  int*   cur    = (int*)(ws + CUR_OFF);
  int*   bsum   = (int*)(ws + BSUM_OFF);
  int*   srcidx = (int*)(ws + SRC_OFF);

  hipMemsetAsync(deg, 0, (size_t)N_NODES * 4, stream);

  k_ln_relu<<<N_NODES / 4, 256, 0, stream>>>(x, lw, lb, h);
  k_pack_w<<<(256 * 128) / 256, 256, 0, stream>>>(Wl, Wr, wt);
  k_count<<<E_EDGES / 256, 256, 0, stream>>>(ei, deg);
  k_scan1<<<SCAN_BLOCKS, 256, 0, stream>>>(deg, offs, bsum);
  k_scan2<<<1, 128, 0, stream>>>(bsum);
  k_scan3<<<(N_NODES + 256) / 256, 256, 0, stream>>>(offs, bsum, cur);
  k_fill<<<E_EDGES / 256, 256, 0, stream>>>(ei, cur, srcidx);
  k_gather_gemm<<<N_NODES / TM, 256, 0, stream>>>(h, wt, bl, offs, srcidx, out);
}

// Round 3
// 478.667 us; speedup vs baseline: 6.3153x; 1.3069x over previous
//
#include <hip/hip_runtime.h>

#define N_NODES 100000
#define E_EDGES 1600000
#define DIM     128

// Workspace layout (bytes), total ~33.4 MiB:
#define HB_OFF   0            // h packed bf16: N*64 u32 = 25,600,000
#define WT_OFF   25600000     // 256*128 f32 = 131,072
#define DEG_OFF  25731072     // N int
#define OFFS_OFF 26131072     // N+1 int (pad 8)
#define CUR_OFF  26531080     // N int
#define BSUM_OFF 26931080     // 98 int (pad 512)
#define SRC_OFF  26931592     // E int

#define SCAN_BLOCKS 98

// ---------- bf16 pack/unpack (RNE) ----------
__device__ __forceinline__ unsigned bf16pack(float a, float b) {
  unsigned ua = __float_as_uint(a); ua += 0x7fffu + ((ua >> 16) & 1u);
  unsigned ub = __float_as_uint(b); ub += 0x7fffu + ((ub >> 16) & 1u);
  return (ua >> 16) | (ub & 0xffff0000u);
}
__device__ __forceinline__ float2 bf16unpack(unsigned p) {
  return make_float2(__uint_as_float(p << 16), __uint_as_float(p & 0xffff0000u));
}

// ---------------- LayerNorm + ReLU -> packed bf16 h --------------------------
__global__ __launch_bounds__(256) void k_ln_relu(const float* __restrict__ x,
                                                 const float* __restrict__ lw,
                                                 const float* __restrict__ lb,
                                                 unsigned* __restrict__ hb) {
  int row  = blockIdx.x * 4 + (threadIdx.x >> 6);
  int lane = threadIdx.x & 63;
  float2 v = ((const float2*)(x + (size_t)row * DIM))[lane];
  float s  = v.x + v.y;
  float sq = v.x * v.x + v.y * v.y;
  #pragma unroll
  for (int off = 32; off > 0; off >>= 1) {
    s  += __shfl_xor(s, off);
    sq += __shfl_xor(sq, off);
  }
  float mu  = s * (1.0f / 128.0f);
  float var = sq * (1.0f / 128.0f) - mu * mu;
  float rs  = rsqrtf(var + 1e-5f);
  float2 w = ((const float2*)lw)[lane];
  float2 b = ((const float2*)lb)[lane];
  float ox = fmaxf((v.x - mu) * rs * w.x + b.x, 0.0f);
  float oy = fmaxf((v.y - mu) * rs * w.y + b.y, 0.0f);
  hb[(size_t)row * 64 + lane] = bf16pack(ox, oy);
}

// ---------------- pack transposed concat weights WcatT[k][c] -----------------
__global__ __launch_bounds__(256) void k_pack_w(const float* __restrict__ Wl,
                                                const float* __restrict__ Wr,
                                                float* __restrict__ wt) {
  int i = blockIdx.x * 256 + threadIdx.x;  // 0..32767
  int k = i >> 7;
  int c = i & 127;
  wt[i] = (k < 128) ? Wl[c * 128 + k] : Wr[c * 128 + (k - 128)];
}

// ---------------- degree histogram (4 edges/thread) --------------------------
__global__ __launch_bounds__(256) void k_count(const int* __restrict__ ei,
                                               int* __restrict__ deg) {
  int i = blockIdx.x * 256 + threadIdx.x;
  if (i >= E_EDGES / 4) return;
  int4 d = ((const int4*)(ei + E_EDGES))[i];
  atomicAdd(&deg[d.x], 1);
  atomicAdd(&deg[d.y], 1);
  atomicAdd(&deg[d.z], 1);
  atomicAdd(&deg[d.w], 1);
}

// ---------------- scan stage 1 ----------------------------------------------
__global__ __launch_bounds__(256) void k_scan1(const int* __restrict__ deg,
                                               int* __restrict__ offs,
                                               int* __restrict__ bsum) {
  __shared__ int s[256];
  int t = threadIdx.x;
  int base = blockIdx.x * 1024 + t * 4;
  int a0 = (base + 0 < N_NODES) ? deg[base + 0] : 0;
  int a1 = (base + 1 < N_NODES) ? deg[base + 1] : 0;
  int a2 = (base + 2 < N_NODES) ? deg[base + 2] : 0;
  int a3 = (base + 3 < N_NODES) ? deg[base + 3] : 0;
  s[t] = a0 + a1 + a2 + a3;
  __syncthreads();
  #pragma unroll
  for (int off = 1; off < 256; off <<= 1) {
    int x = (t >= off) ? s[t - off] : 0;
    __syncthreads();
    s[t] += x;
    __syncthreads();
  }
  int excl = (t > 0) ? s[t - 1] : 0;
  if (t == 255) bsum[blockIdx.x] = s[255];
  if (base + 0 < N_NODES) offs[base + 0] = excl;
  if (base + 1 < N_NODES) offs[base + 1] = excl + a0;
  if (base + 2 < N_NODES) offs[base + 2] = excl + a0 + a1;
  if (base + 3 < N_NODES) offs[base + 3] = excl + a0 + a1 + a2;
}

// ---------------- scan stage 2 ----------------------------------------------
__global__ __launch_bounds__(128) void k_scan2(int* __restrict__ bsum) {
  __shared__ int s[128];
  int t = threadIdx.x;
  int v = (t < SCAN_BLOCKS) ? bsum[t] : 0;
  s[t] = v;
  __syncthreads();
  #pragma unroll
  for (int off = 1; off < 128; off <<= 1) {
    int x = (t >= off) ? s[t - off] : 0;
    __syncthreads();
    s[t] += x;
    __syncthreads();
  }
  if (t < SCAN_BLOCKS) bsum[t] = (t > 0) ? s[t - 1] : 0;
}

// ---------------- scan stage 3 ----------------------------------------------
__global__ __launch_bounds__(256) void k_scan3(int* __restrict__ offs,
                                               const int* __restrict__ bsum,
                                               int* __restrict__ cur) {
  int i = blockIdx.x * 256 + threadIdx.x;
  if (i < N_NODES) {
    int v = offs[i] + bsum[i >> 10];
    offs[i] = v;
    cur[i] = v;
  }
  if (i == N_NODES) offs[N_NODES] = E_EDGES;
}

// ---------------- CSR fill (4 edges/thread) ----------------------------------
__global__ __launch_bounds__(256) void k_fill(const int* __restrict__ ei,
                                              int* __restrict__ cur,
                                              int* __restrict__ srcidx) {
  int i = blockIdx.x * 256 + threadIdx.x;
  if (i >= E_EDGES / 4) return;
  int4 s = ((const int4*)ei)[i];
  int4 d = ((const int4*)(ei + E_EDGES))[i];
  int p0 = atomicAdd(&cur[d.x], 1); srcidx[p0] = s.x;
  int p1 = atomicAdd(&cur[d.y], 1); srcidx[p1] = s.y;
  int p2 = atomicAdd(&cur[d.z], 1); srcidx[p2] = s.z;
  int p3 = atomicAdd(&cur[d.w], 1); srcidx[p3] = s.w;
}

// ---------------- fused gather + mean + GEMM ---------------------------------
// Phase 1: each wave gathers 8 rows; neighbor loop is wave-uniform (scalar
// index loads) and unrolled x4 for 4 outstanding 256B vector loads.
// Phase 2: 4x4 register-tile f32 GEMM vs WcatT (K=256), float4 LDS reads.
#define TM    32
#define PITCH 260
__global__ __launch_bounds__(256) void k_gather_gemm(const unsigned* __restrict__ hb,
                                                     const float* __restrict__ wt,
                                                     const float* __restrict__ bl,
                                                     const int* __restrict__ offs,
                                                     const int* __restrict__ srcidx,
                                                     float* __restrict__ out) {
  __shared__ float A[TM * PITCH];
  int tid  = threadIdx.x;
  int wave = tid >> 6;
  int lane = tid & 63;
  int rbase = blockIdx.x * TM;

  // Phase 1: gather
  for (int r8 = 0; r8 < 8; ++r8) {
    int row = wave * 8 + r8;
    int n   = rbase + row;
    int beg = __builtin_amdgcn_readfirstlane(offs[n]);
    int end = __builtin_amdgcn_readfirstlane(offs[n + 1]);
    float ax = 0.0f, ay = 0.0f;
    int j = beg;
    for (; j + 4 <= end; j += 4) {
      int s0 = srcidx[j + 0];
      int s1 = srcidx[j + 1];
      int s2 = srcidx[j + 2];
      int s3 = srcidx[j + 3];
      unsigned p0 = hb[(size_t)s0 * 64 + lane];
      unsigned p1 = hb[(size_t)s1 * 64 + lane];
      unsigned p2 = hb[(size_t)s2 * 64 + lane];
      unsigned p3 = hb[(size_t)s3 * 64 + lane];
      float2 v0 = bf16unpack(p0);
      float2 v1 = bf16unpack(p1);
      float2 v2 = bf16unpack(p2);
      float2 v3 = bf16unpack(p3);
      ax += (v0.x + v1.x) + (v2.x + v3.x);
      ay += (v0.y + v1.y) + (v2.y + v3.y);
    }
    for (; j < end; ++j) {
      unsigned p = hb[(size_t)srcidx[j] * 64 + lane];
      float2 v = bf16unpack(p);
      ax += v.x; ay += v.y;
    }
    float inv = 1.0f / fmaxf((float)(end - beg), 1.0f);
    float2 hv = bf16unpack(hb[(size_t)n * 64 + lane]);
    *((float2*)&A[row * PITCH + lane * 2])       = make_float2(ax * inv, ay * inv);
    *((float2*)&A[row * PITCH + 128 + lane * 2]) = hv;
  }
  __syncthreads();

  // Phase 2: GEMM
  int tx = tid & 31;
  int ty = tid >> 5;
  float acc[4][4];
  #pragma unroll
  for (int i = 0; i < 4; ++i)
    #pragma unroll
    for (int j = 0; j < 4; ++j) acc[i][j] = 0.0f;

  const float* Abase = &A[(ty * 4) * PITCH];
  const float4* wt4 = (const float4*)wt;
  for (int k = 0; k < 256; k += 4) {
    float a0[4], a1[4], a2[4], a3[4];
    *(float4*)a0 = *(const float4*)&Abase[0 * PITCH + k];
    *(float4*)a1 = *(const float4*)&Abase[1 * PITCH + k];
    *(float4*)a2 = *(const float4*)&Abase[2 * PITCH + k];
    *(float4*)a3 = *(const float4*)&Abase[3 * PITCH + k];
    #pragma unroll
    for (int kk = 0; kk < 4; ++kk) {
      float4 w = wt4[(k + kk) * 32 + tx];
      acc[0][0] += a0[kk] * w.x; acc[0][1] += a0[kk] * w.y; acc[0][2] += a0[kk] * w.z; acc[0][3] += a0[kk] * w.w;
      acc[1][0] += a1[kk] * w.x; acc[1][1] += a1[kk] * w.y; acc[1][2] += a1[kk] * w.z; acc[1][3] += a1[kk] * w.w;
      acc[2][0] += a2[kk] * w.x; acc[2][1] += a2[kk] * w.y; acc[2][2] += a2[kk] * w.z; acc[2][3] += a2[kk] * w.w;
      acc[3][0] += a3[kk] * w.x; acc[3][1] += a3[kk] * w.y; acc[3][2] += a3[kk] * w.z; acc[3][3] += a3[kk] * w.w;
    }
  }

  float4 bias = ((const float4*)bl)[tx];
  #pragma unroll
  for (int i = 0; i < 4; ++i) {
    float4 o;
    o.x = acc[i][0] + bias.x;
    o.y = acc[i][1] + bias.y;
    o.z = acc[i][2] + bias.z;
    o.w = acc[i][3] + bias.w;
    ((float4*)(out + (size_t)(rbase + ty * 4 + i) * DIM))[tx] = o;
  }
}

extern "C" void kernel_launch(void* const* d_in, const int* in_sizes, int n_in,
                              void* d_out, int out_size, void* d_ws, size_t ws_size,
                              hipStream_t stream) {
  const float* x  = (const float*)d_in[0];
  const int*   ei = (const int*)d_in[1];   // [2, E] int32
  const float* lw = (const float*)d_in[2];
  const float* lb = (const float*)d_in[3];
  const float* Wl = (const float*)d_in[4];
  const float* bl = (const float*)d_in[5];
  const float* Wr = (const float*)d_in[6];
  float* out = (float*)d_out;

  char* ws = (char*)d_ws;
  unsigned* hb     = (unsigned*)(ws + HB_OFF);
  float*    wt     = (float*)(ws + WT_OFF);
  int*      deg    = (int*)(ws + DEG_OFF);
  int*      offs   = (int*)(ws + OFFS_OFF);
  int*      cur    = (int*)(ws + CUR_OFF);
  int*      bsum   = (int*)(ws + BSUM_OFF);
  int*      srcidx = (int*)(ws + SRC_OFF);

  hipMemsetAsync(deg, 0, (size_t)N_NODES * 4, stream);

  k_ln_relu<<<N_NODES / 4, 256, 0, stream>>>(x, lw, lb, hb);
  k_pack_w<<<(256 * 128) / 256, 256, 0, stream>>>(Wl, Wr, wt);
  k_count<<<(E_EDGES / 4 + 255) / 256, 256, 0, stream>>>(ei, deg);
  k_scan1<<<SCAN_BLOCKS, 256, 0, stream>>>(deg, offs, bsum);
  k_scan2<<<1, 128, 0, stream>>>(bsum);
  k_scan3<<<(N_NODES + 256) / 256, 256, 0, stream>>>(offs, bsum, cur);
  k_fill<<<(E_EDGES / 4 + 255) / 256, 256, 0, stream>>>(ei, cur, srcidx);
  k_gather_gemm<<<N_NODES / TM, 256, 0, stream>>>(hb, wt, bl, offs, srcidx, out);
}

// Round 4
// 405.870 us; speedup vs baseline: 7.4480x; 1.1794x over previous
//
#include <hip/hip_runtime.h>

#define N_NODES 100000
#define E_EDGES 1600000
#define DIM     128

// Workspace layout (bytes), total ~58.9 MiB:
#define HB_OFF   0            // h packed bf16: N*64 u32 = 25,600,000
#define AGGB_OFF 25600000     // mean-agg packed bf16: N*64 u32 = 25,600,000
#define WTB_OFF  51200000     // WcatT bf16 in MFMA-B-fragment layout: 16384 u32 = 65,536
#define DEG_OFF  51265536     // N int
#define OFFS_OFF 51665536     // N+1 int (pad 8)
#define CUR_OFF  52065544     // N int
#define BSUM_OFF 52465544     // 98 int (pad 512)
#define SRC_OFF  52466056     // E int

#define SCAN_BLOCKS 98

typedef __attribute__((ext_vector_type(8))) short short8;
typedef __attribute__((ext_vector_type(4))) float floatx4;

// ---------- bf16 pack/unpack (RNE) ----------
__device__ __forceinline__ unsigned bf16pack(float a, float b) {
  unsigned ua = __float_as_uint(a); ua += 0x7fffu + ((ua >> 16) & 1u);
  unsigned ub = __float_as_uint(b); ub += 0x7fffu + ((ub >> 16) & 1u);
  return (ua >> 16) | (ub & 0xffff0000u);
}
__device__ __forceinline__ float2 bf16unpack(unsigned p) {
  return make_float2(__uint_as_float(p << 16), __uint_as_float(p & 0xffff0000u));
}

// ------------- prep: LayerNorm+ReLU -> hb, degree count, weight pack ---------
// grid 25000 x 256. LN: 4 rows/block. count: first 400000 threads, 4 edges each.
// pack: first 16384 threads build wtbf in MFMA B-fragment layout:
//   u32 idx i = kb*2048 + c*16 + q*4 + j2  ->  (k = kb*32 + q*8 + 2*j2 {,+1}, col c)
__global__ __launch_bounds__(256) void k_prep(const float* __restrict__ x,
                                              const float* __restrict__ lw,
                                              const float* __restrict__ lb,
                                              const float* __restrict__ Wl,
                                              const float* __restrict__ Wr,
                                              const int* __restrict__ ei,
                                              unsigned* __restrict__ hb,
                                              int* __restrict__ deg,
                                              unsigned* __restrict__ wtb) {
  int gid = blockIdx.x * 256 + threadIdx.x;

  // --- LN+ReLU ---
  {
    int row  = blockIdx.x * 4 + (threadIdx.x >> 6);
    int lane = threadIdx.x & 63;
    float2 v = ((const float2*)(x + (size_t)row * DIM))[lane];
    float s  = v.x + v.y;
    float sq = v.x * v.x + v.y * v.y;
    #pragma unroll
    for (int off = 32; off > 0; off >>= 1) {
      s  += __shfl_xor(s, off);
      sq += __shfl_xor(sq, off);
    }
    float mu  = s * (1.0f / 128.0f);
    float var = sq * (1.0f / 128.0f) - mu * mu;
    float rs  = rsqrtf(var + 1e-5f);
    float2 w = ((const float2*)lw)[lane];
    float2 b = ((const float2*)lb)[lane];
    float ox = fmaxf((v.x - mu) * rs * w.x + b.x, 0.0f);
    float oy = fmaxf((v.y - mu) * rs * w.y + b.y, 0.0f);
    hb[(size_t)row * 64 + lane] = bf16pack(ox, oy);
  }

  // --- degree histogram (4 edges/thread) ---
  if (gid < E_EDGES / 4) {
    int4 d = ((const int4*)(ei + E_EDGES))[gid];
    atomicAdd(&deg[d.x], 1);
    atomicAdd(&deg[d.y], 1);
    atomicAdd(&deg[d.z], 1);
    atomicAdd(&deg[d.w], 1);
  }

  // --- weight pack (bf16, B-fragment layout) ---
  if (gid < 16384) {
    int j2 = gid & 3;
    int q  = (gid >> 2) & 3;
    int c  = (gid >> 4) & 127;
    int kb = gid >> 11;
    int k0 = kb * 32 + q * 8 + j2 * 2;
    int k1 = k0 + 1;
    float v0 = (k0 < 128) ? Wl[c * 128 + k0] : Wr[c * 128 + (k0 - 128)];
    float v1 = (k1 < 128) ? Wl[c * 128 + k1] : Wr[c * 128 + (k1 - 128)];
    wtb[gid] = bf16pack(v0, v1);
  }
}

// ---------------- scan stage 1: per-block exclusive scan (1024 elems) --------
__global__ __launch_bounds__(256) void k_scan1(const int* __restrict__ deg,
                                               int* __restrict__ offs,
                                               int* __restrict__ bsum) {
  __shared__ int s[256];
  int t = threadIdx.x;
  int base = blockIdx.x * 1024 + t * 4;
  int a0 = (base + 0 < N_NODES) ? deg[base + 0] : 0;
  int a1 = (base + 1 < N_NODES) ? deg[base + 1] : 0;
  int a2 = (base + 2 < N_NODES) ? deg[base + 2] : 0;
  int a3 = (base + 3 < N_NODES) ? deg[base + 3] : 0;
  s[t] = a0 + a1 + a2 + a3;
  __syncthreads();
  #pragma unroll
  for (int off = 1; off < 256; off <<= 1) {
    int x = (t >= off) ? s[t - off] : 0;
    __syncthreads();
    s[t] += x;
    __syncthreads();
  }
  int excl = (t > 0) ? s[t - 1] : 0;
  if (t == 255) bsum[blockIdx.x] = s[255];
  if (base + 0 < N_NODES) offs[base + 0] = excl;
  if (base + 1 < N_NODES) offs[base + 1] = excl + a0;
  if (base + 2 < N_NODES) offs[base + 2] = excl + a0 + a1;
  if (base + 3 < N_NODES) offs[base + 3] = excl + a0 + a1 + a2;
}

// -------- scan stage 2+3 fused: each block re-scans 98 bsums locally ---------
__global__ __launch_bounds__(256) void k_scan23(int* __restrict__ offs,
                                                const int* __restrict__ bsum,
                                                int* __restrict__ cur) {
  __shared__ int s[128];
  int t = threadIdx.x;
  if (t < 128) s[t] = (t < SCAN_BLOCKS) ? bsum[t] : 0;
  __syncthreads();
  if (t < 128) {
    #pragma unroll
    for (int off = 1; off < 128; off <<= 1) {
      int x = (t >= off) ? s[t - off] : 0;
      __syncthreads();
      s[t] += x;
      __syncthreads();
    }
  } else {
    #pragma unroll
    for (int off = 1; off < 128; off <<= 1) { __syncthreads(); __syncthreads(); }
  }
  int blk = blockIdx.x;           // 1024 elems per block
  int base = (blk > 0) ? s[blk - 1] : 0;
  #pragma unroll
  for (int u = 0; u < 4; ++u) {
    int i = blk * 1024 + t * 4 + u;  // strideless within thread, ok
    if (i < N_NODES) {
      int v = offs[i] + base;
      offs[i] = v;
      cur[i] = v;
    }
    if (i == N_NODES) offs[N_NODES] = E_EDGES;
  }
}

// ---------------- CSR fill (4 edges/thread) ----------------------------------
__global__ __launch_bounds__(256) void k_fill(const int* __restrict__ ei,
                                              int* __restrict__ cur,
                                              int* __restrict__ srcidx) {
  int i = blockIdx.x * 256 + threadIdx.x;
  if (i >= E_EDGES / 4) return;
  int4 s = ((const int4*)ei)[i];
  int4 d = ((const int4*)(ei + E_EDGES))[i];
  int p0 = atomicAdd(&cur[d.x], 1); srcidx[p0] = s.x;
  int p1 = atomicAdd(&cur[d.y], 1); srcidx[p1] = s.y;
  int p2 = atomicAdd(&cur[d.z], 1); srcidx[p2] = s.z;
  int p3 = atomicAdd(&cur[d.w], 1); srcidx[p3] = s.w;
}

// ---------------- gather + mean -> aggb (bf16) -------------------------------
// One wave per node. No LDS -> high occupancy. Unroll x8 -> 8 outstanding
// 256B row loads per wave. Wave-uniform indices via readfirstlane -> s_load.
__global__ __launch_bounds__(256) void k_gather(const unsigned* __restrict__ hb,
                                                const int* __restrict__ offs,
                                                const int* __restrict__ srcidx,
                                                unsigned* __restrict__ aggb) {
  int wave = threadIdx.x >> 6;
  int lane = threadIdx.x & 63;
  int n = blockIdx.x * 4 + wave;
  int beg = __builtin_amdgcn_readfirstlane(offs[n]);
  int end = __builtin_amdgcn_readfirstlane(offs[n + 1]);
  float ax = 0.0f, ay = 0.0f;
  for (int j0 = beg; j0 < end; j0 += 8) {
    #pragma unroll
    for (int i = 0; i < 8; ++i) {
      int jj = j0 + i;
      int js = (jj < end) ? jj : (end - 1);   // clamp: keep srcidx read in-bounds
      int s  = srcidx[js];                    // wave-uniform -> scalar load
      unsigned p = hb[(size_t)s * 64 + lane];
      p = (jj < end) ? p : 0u;
      float2 v = bf16unpack(p);
      ax += v.x; ay += v.y;
    }
  }
  float inv = 1.0f / fmaxf((float)(end - beg), 1.0f);
  aggb[(size_t)n * 64 + lane] = bf16pack(ax * inv, ay * inv);
}

// ---------------- bf16 MFMA GEMM: out = [aggb|hb] @ WcatT^T + b_l ------------
// Block 256 = 4 waves; each wave: 16 rows x 128 cols, K=256 (8 kb-steps of 32).
// A-frags direct from global (16B/lane), B-frags from pre-packed wtb.
__global__ __launch_bounds__(256) void k_gemm(const unsigned* __restrict__ aggb,
                                              const unsigned* __restrict__ hb,
                                              const unsigned* __restrict__ wtb,
                                              const float* __restrict__ bl,
                                              float* __restrict__ out) {
  int wave = threadIdx.x >> 6;
  int lane = threadIdx.x & 63;
  int m = lane & 15;
  int q = lane >> 4;
  int r0 = blockIdx.x * 64 + wave * 16;
  int rowA = r0 + m;
  if (rowA > N_NODES - 1) rowA = N_NODES - 1;  // tail clamp (stores guarded)

  // Load 8 A-fragments: kb 0..3 from aggb, 4..7 from hb.
  const uint4* ar = (const uint4*)(aggb + (size_t)rowA * 64);
  const uint4* hr = (const uint4*)(hb + (size_t)rowA * 64);
  short8 afrag[8];
  #pragma unroll
  for (int kb = 0; kb < 4; ++kb) {
    uint4 u = ar[kb * 4 + q];
    afrag[kb] = *(short8*)&u;
  }
  #pragma unroll
  for (int kb = 0; kb < 4; ++kb) {
    uint4 u = hr[kb * 4 + q];
    afrag[kb + 4] = *(short8*)&u;
  }

  const uint4* b4 = (const uint4*)wtb;
  #pragma unroll
  for (int ct = 0; ct < 8; ++ct) {
    int c0 = ct * 16;
    int c  = c0 + m;
    floatx4 acc = {0.0f, 0.0f, 0.0f, 0.0f};
    #pragma unroll
    for (int kb = 0; kb < 8; ++kb) {
      uint4 u = b4[kb * 512 + c * 4 + q];
      short8 bfrag = *(short8*)&u;
      acc = __builtin_amdgcn_mfma_f32_16x16x32_bf16(afrag[kb], bfrag, acc, 0, 0, 0);
    }
    float bias = bl[c];
    #pragma unroll
    for (int reg = 0; reg < 4; ++reg) {
      int r = r0 + q * 4 + reg;
      if (r < N_NODES) out[(size_t)r * DIM + c] = acc[reg] + bias;
    }
  }
}

extern "C" void kernel_launch(void* const* d_in, const int* in_sizes, int n_in,
                              void* d_out, int out_size, void* d_ws, size_t ws_size,
                              hipStream_t stream) {
  const float* x  = (const float*)d_in[0];
  const int*   ei = (const int*)d_in[1];   // [2, E] int32
  const float* lw = (const float*)d_in[2];
  const float* lb = (const float*)d_in[3];
  const float* Wl = (const float*)d_in[4];
  const float* bl = (const float*)d_in[5];
  const float* Wr = (const float*)d_in[6];
  float* out = (float*)d_out;

  char* ws = (char*)d_ws;
  unsigned* hb     = (unsigned*)(ws + HB_OFF);
  unsigned* aggb   = (unsigned*)(ws + AGGB_OFF);
  unsigned* wtb    = (unsigned*)(ws + WTB_OFF);
  int*      deg    = (int*)(ws + DEG_OFF);
  int*      offs   = (int*)(ws + OFFS_OFF);
  int*      cur    = (int*)(ws + CUR_OFF);
  int*      bsum   = (int*)(ws + BSUM_OFF);
  int*      srcidx = (int*)(ws + SRC_OFF);

  hipMemsetAsync(deg, 0, (size_t)N_NODES * 4, stream);

  k_prep<<<N_NODES / 4, 256, 0, stream>>>(x, lw, lb, Wl, Wr, ei, hb, deg, wtb);
  k_scan1<<<SCAN_BLOCKS, 256, 0, stream>>>(deg, offs, bsum);
  k_scan23<<<SCAN_BLOCKS, 256, 0, stream>>>(offs, bsum, cur);
  k_fill<<<(E_EDGES / 4 + 255) / 256, 256, 0, stream>>>(ei, cur, srcidx);
  k_gather<<<N_NODES / 4, 256, 0, stream>>>(hb, offs, srcidx, aggb);
  k_gemm<<<(N_NODES + 63) / 64, 256, 0, stream>>>(aggb, hb, wtb, bl, out);
}

// Round 5
// 333.161 us; speedup vs baseline: 9.0734x; 1.2182x over previous
//
#include <hip/hip_runtime.h>

#define N_NODES 100000
#define E_EDGES 1600000
#define DIM     128

// Workspace layout (bytes), total ~65.3 MiB:
#define HB_OFF   0            // h packed bf16: N*64 u32 = 25,600,000
#define AGGB_OFF 25600000     // mean-agg packed bf16: N*64 u32 = 25,600,000
#define WTB_OFF  51200000     // WcatT bf16 B-fragment layout: 16384 u32 = 65,536
#define DEG_OFF  51265536     // N int
#define OFFS_OFF 51665536     // N+1 int (pad 8)
#define BSUM_OFF 52065544     // 98 int (pad 512)
#define SRC_OFF  52066056     // E int = 6,400,000
#define RANK_OFF 58466056     // E int = 6,400,000 -> end 64,866,056

#define SCAN_BLOCKS 98

typedef __attribute__((ext_vector_type(8))) short short8;
typedef __attribute__((ext_vector_type(4))) float floatx4;

// ---------- bf16 pack/unpack (RNE) ----------
__device__ __forceinline__ unsigned bf16pack(float a, float b) {
  unsigned ua = __float_as_uint(a); ua += 0x7fffu + ((ua >> 16) & 1u);
  unsigned ub = __float_as_uint(b); ub += 0x7fffu + ((ub >> 16) & 1u);
  return (ua >> 16) | (ub & 0xffff0000u);
}
__device__ __forceinline__ float2 bf16unpack(unsigned p) {
  return make_float2(__uint_as_float(p << 16), __uint_as_float(p & 0xffff0000u));
}

// ------------- prep: LayerNorm+ReLU -> hb, degree+rank, weight pack ----------
__global__ __launch_bounds__(256) void k_prep(const float* __restrict__ x,
                                              const float* __restrict__ lw,
                                              const float* __restrict__ lb,
                                              const float* __restrict__ Wl,
                                              const float* __restrict__ Wr,
                                              const int* __restrict__ ei,
                                              unsigned* __restrict__ hb,
                                              int* __restrict__ deg,
                                              int* __restrict__ rank,
                                              unsigned* __restrict__ wtb) {
  int gid = blockIdx.x * 256 + threadIdx.x;

  // --- LN+ReLU ---
  {
    int row  = blockIdx.x * 4 + (threadIdx.x >> 6);
    int lane = threadIdx.x & 63;
    float2 v = ((const float2*)(x + (size_t)row * DIM))[lane];
    float s  = v.x + v.y;
    float sq = v.x * v.x + v.y * v.y;
    #pragma unroll
    for (int off = 32; off > 0; off >>= 1) {
      s  += __shfl_xor(s, off);
      sq += __shfl_xor(sq, off);
    }
    float mu  = s * (1.0f / 128.0f);
    float var = sq * (1.0f / 128.0f) - mu * mu;
    float rs  = rsqrtf(var + 1e-5f);
    float2 w = ((const float2*)lw)[lane];
    float2 b = ((const float2*)lb)[lane];
    float ox = fmaxf((v.x - mu) * rs * w.x + b.x, 0.0f);
    float oy = fmaxf((v.y - mu) * rs * w.y + b.y, 0.0f);
    hb[(size_t)row * 64 + lane] = bf16pack(ox, oy);
  }

  // --- degree histogram + per-edge rank (4 edges/thread, coalesced rank) ---
  if (gid < E_EDGES / 4) {
    int4 d = ((const int4*)(ei + E_EDGES))[gid];
    int4 r;
    r.x = atomicAdd(&deg[d.x], 1);
    r.y = atomicAdd(&deg[d.y], 1);
    r.z = atomicAdd(&deg[d.z], 1);
    r.w = atomicAdd(&deg[d.w], 1);
    ((int4*)rank)[gid] = r;
  }

  // --- weight pack (bf16, B-fragment layout) ---
  if (gid < 16384) {
    int j2 = gid & 3;
    int q  = (gid >> 2) & 3;
    int c  = (gid >> 4) & 127;
    int kb = gid >> 11;
    int k0 = kb * 32 + q * 8 + j2 * 2;
    int k1 = k0 + 1;
    float v0 = (k0 < 128) ? Wl[c * 128 + k0] : Wr[c * 128 + (k0 - 128)];
    float v1 = (k1 < 128) ? Wl[c * 128 + k1] : Wr[c * 128 + (k1 - 128)];
    wtb[gid] = bf16pack(v0, v1);
  }
}

// ---------------- scan stage 1: per-block exclusive scan (1024 elems) --------
__global__ __launch_bounds__(256) void k_scan1(const int* __restrict__ deg,
                                               int* __restrict__ offs,
                                               int* __restrict__ bsum) {
  __shared__ int s[256];
  int t = threadIdx.x;
  int base = blockIdx.x * 1024 + t * 4;
  int a0 = (base + 0 < N_NODES) ? deg[base + 0] : 0;
  int a1 = (base + 1 < N_NODES) ? deg[base + 1] : 0;
  int a2 = (base + 2 < N_NODES) ? deg[base + 2] : 0;
  int a3 = (base + 3 < N_NODES) ? deg[base + 3] : 0;
  s[t] = a0 + a1 + a2 + a3;
  __syncthreads();
  #pragma unroll
  for (int off = 1; off < 256; off <<= 1) {
    int x = (t >= off) ? s[t - off] : 0;
    __syncthreads();
    s[t] += x;
    __syncthreads();
  }
  int excl = (t > 0) ? s[t - 1] : 0;
  if (t == 255) bsum[blockIdx.x] = s[255];
  if (base + 0 < N_NODES) offs[base + 0] = excl;
  if (base + 1 < N_NODES) offs[base + 1] = excl + a0;
  if (base + 2 < N_NODES) offs[base + 2] = excl + a0 + a1;
  if (base + 3 < N_NODES) offs[base + 3] = excl + a0 + a1 + a2;
}

// -------- scan stage 2+3 fused: each block re-scans 98 bsums locally ---------
__global__ __launch_bounds__(256) void k_scan23(int* __restrict__ offs,
                                                const int* __restrict__ bsum) {
  __shared__ int s[128];
  int t = threadIdx.x;
  if (t < 128) s[t] = (t < SCAN_BLOCKS) ? bsum[t] : 0;
  __syncthreads();
  if (t < 128) {
    #pragma unroll
    for (int off = 1; off < 128; off <<= 1) {
      int x = (t >= off) ? s[t - off] : 0;
      __syncthreads();
      s[t] += x;
      __syncthreads();
    }
  } else {
    #pragma unroll
    for (int off = 1; off < 128; off <<= 1) { __syncthreads(); __syncthreads(); }
  }
  int blk = blockIdx.x;
  int base = (blk > 0) ? s[blk - 1] : 0;
  #pragma unroll
  for (int u = 0; u < 4; ++u) {
    int i = blk * 1024 + t * 4 + u;
    if (i < N_NODES) offs[i] += base;
    if (i == N_NODES) offs[N_NODES] = E_EDGES;
  }
}

// ---------------- CSR fill: atomic-free via precomputed rank -----------------
__global__ __launch_bounds__(256) void k_fill(const int* __restrict__ ei,
                                              const int* __restrict__ offs,
                                              const int* __restrict__ rank,
                                              int* __restrict__ srcidx) {
  int i = blockIdx.x * 256 + threadIdx.x;
  if (i >= E_EDGES / 4) return;
  int4 s = ((const int4*)ei)[i];
  int4 d = ((const int4*)(ei + E_EDGES))[i];
  int4 r = ((const int4*)rank)[i];
  srcidx[offs[d.x] + r.x] = s.x;
  srcidx[offs[d.y] + r.y] = s.y;
  srcidx[offs[d.z] + r.z] = s.z;
  srcidx[offs[d.w] + r.w] = s.w;
}

// ---------------- gather + mean -> aggb (bf16) -------------------------------
// One wave per node, no LDS. Full groups of 8 (8 outstanding 256B row loads),
// then scalar tail — no wasted clamped loads.
__global__ __launch_bounds__(256) void k_gather(const unsigned* __restrict__ hb,
                                                const int* __restrict__ offs,
                                                const int* __restrict__ srcidx,
                                                unsigned* __restrict__ aggb) {
  int wave = threadIdx.x >> 6;
  int lane = threadIdx.x & 63;
  int n = blockIdx.x * 4 + wave;
  int beg = __builtin_amdgcn_readfirstlane(offs[n]);
  int end = __builtin_amdgcn_readfirstlane(offs[n + 1]);
  int deg = end - beg;
  int full = beg + (deg & ~7);
  float ax = 0.0f, ay = 0.0f;
  for (int j0 = beg; j0 < full; j0 += 8) {
    #pragma unroll
    for (int i = 0; i < 8; ++i) {
      int s = srcidx[j0 + i];                 // wave-uniform -> scalar load
      unsigned p = hb[(size_t)s * 64 + lane];
      float2 v = bf16unpack(p);
      ax += v.x; ay += v.y;
    }
  }
  for (int j = full; j < end; ++j) {
    int s = srcidx[j];
    unsigned p = hb[(size_t)s * 64 + lane];
    float2 v = bf16unpack(p);
    ax += v.x; ay += v.y;
  }
  float inv = 1.0f / fmaxf((float)deg, 1.0f);
  aggb[(size_t)n * 64 + lane] = bf16pack(ax * inv, ay * inv);
}

// ---------------- bf16 MFMA GEMM: out = [aggb|hb] @ WcatT^T + b_l ------------
__global__ __launch_bounds__(256) void k_gemm(const unsigned* __restrict__ aggb,
                                              const unsigned* __restrict__ hb,
                                              const unsigned* __restrict__ wtb,
                                              const float* __restrict__ bl,
                                              float* __restrict__ out) {
  int wave = threadIdx.x >> 6;
  int lane = threadIdx.x & 63;
  int m = lane & 15;
  int q = lane >> 4;
  int r0 = blockIdx.x * 64 + wave * 16;
  int rowA = r0 + m;
  if (rowA > N_NODES - 1) rowA = N_NODES - 1;  // tail clamp (stores guarded)

  const uint4* ar = (const uint4*)(aggb + (size_t)rowA * 64);
  const uint4* hr = (const uint4*)(hb + (size_t)rowA * 64);
  short8 afrag[8];
  #pragma unroll
  for (int kb = 0; kb < 4; ++kb) {
    uint4 u = ar[kb * 4 + q];
    afrag[kb] = *(short8*)&u;
  }
  #pragma unroll
  for (int kb = 0; kb < 4; ++kb) {
    uint4 u = hr[kb * 4 + q];
    afrag[kb + 4] = *(short8*)&u;
  }

  const uint4* b4 = (const uint4*)wtb;
  #pragma unroll
  for (int ct = 0; ct < 8; ++ct) {
    int c0 = ct * 16;
    int c  = c0 + m;
    floatx4 acc = {0.0f, 0.0f, 0.0f, 0.0f};
    #pragma unroll
    for (int kb = 0; kb < 8; ++kb) {
      uint4 u = b4[kb * 512 + c * 4 + q];
      short8 bfrag = *(short8*)&u;
      acc = __builtin_amdgcn_mfma_f32_16x16x32_bf16(afrag[kb], bfrag, acc, 0, 0, 0);
    }
    float bias = bl[c];
    #pragma unroll
    for (int reg = 0; reg < 4; ++reg) {
      int r = r0 + q * 4 + reg;
      if (r < N_NODES) out[(size_t)r * DIM + c] = acc[reg] + bias;
    }
  }
}

extern "C" void kernel_launch(void* const* d_in, const int* in_sizes, int n_in,
                              void* d_out, int out_size, void* d_ws, size_t ws_size,
                              hipStream_t stream) {
  const float* x  = (const float*)d_in[0];
  const int*   ei = (const int*)d_in[1];   // [2, E] int32
  const float* lw = (const float*)d_in[2];
  const float* lb = (const float*)d_in[3];
  const float* Wl = (const float*)d_in[4];
  const float* bl = (const float*)d_in[5];
  const float* Wr = (const float*)d_in[6];
  float* out = (float*)d_out;

  char* ws = (char*)d_ws;
  unsigned* hb     = (unsigned*)(ws + HB_OFF);
  unsigned* aggb   = (unsigned*)(ws + AGGB_OFF);
  unsigned* wtb    = (unsigned*)(ws + WTB_OFF);
  int*      deg    = (int*)(ws + DEG_OFF);
  int*      offs   = (int*)(ws + OFFS_OFF);
  int*      bsum   = (int*)(ws + BSUM_OFF);
  int*      srcidx = (int*)(ws + SRC_OFF);
  int*      rank   = (int*)(ws + RANK_OFF);

  hipMemsetAsync(deg, 0, (size_t)N_NODES * 4, stream);

  k_prep<<<N_NODES / 4, 256, 0, stream>>>(x, lw, lb, Wl, Wr, ei, hb, deg, rank, wtb);
  k_scan1<<<SCAN_BLOCKS, 256, 0, stream>>>(deg, offs, bsum);
  k_scan23<<<SCAN_BLOCKS, 256, 0, stream>>>(offs, bsum);
  k_fill<<<(E_EDGES / 4 + 255) / 256, 256, 0, stream>>>(ei, offs, rank, srcidx);
  k_gather<<<N_NODES / 4, 256, 0, stream>>>(hb, offs, srcidx, aggb);
  k_gemm<<<(N_NODES + 63) / 64, 256, 0, stream>>>(aggb, hb, wtb, bl, out);
}